// Round 1
// baseline (6250.047 us; speedup 1.0000x reference)
//
#include <hip/hip_runtime.h>
#include <math.h>

#define NV 50000
#define NR 500
#define EVV 400000
#define EVI 100000
#define EIV 100000

static __device__ __forceinline__ unsigned enc_f(float f) {
  unsigned u = __float_as_uint(f);
  return (u & 0x80000000u) ? ~u : (u | 0x80000000u);
}
static __device__ __forceinline__ float dec_f(unsigned e) {
  unsigned u = (e & 0x80000000u) ? (e & 0x7fffffffu) : ~e;
  return __uint_as_float(u);
}

// out[n,64] = x[n,d] @ W[d,64] + b
__global__ void proj_kernel(const float* __restrict__ x, const float* __restrict__ W,
                            const float* __restrict__ b, float* __restrict__ out,
                            int n, int d) {
  int t = blockIdx.x * blockDim.x + threadIdx.x;
  if (t >= n * 64) return;
  int row = t >> 6, col = t & 63;
  const float* xr = x + row * d;
  float acc = b[col];
  for (int k = 0; k < d; ++k) acc = fmaf(xr[k], W[k * 64 + col], acc);
  out[t] = acc;
}

// Per (edge, head): e = sum_c leakyrelu(hl[src]+hr[dst])*att ; atomicMax into encoded segment max.
// Edges e >= E are self-loops (src=dst=e-E). selfmask: original src==dst edges are invalid.
__global__ void edge_score_kernel(const int* __restrict__ src_a, const int* __restrict__ dst_a,
                                  int E, int total, int selfmask, int hshift, int C,
                                  const float* __restrict__ hl, const float* __restrict__ hr,
                                  const float* __restrict__ att,
                                  float* __restrict__ ebuf, unsigned* __restrict__ emax) {
  int t = blockIdx.x * blockDim.x + threadIdx.x;
  if (t >= total) return;
  int e = t >> hshift, h = t & ((1 << hshift) - 1);
  int s, d2; bool valid;
  if (e < E) { s = src_a[e]; d2 = dst_a[e]; valid = !selfmask || (s != d2); }
  else { s = d2 = e - E; valid = true; }
  int HC = C << hshift;
  const float* pl = hl + s * HC + h * C;
  const float* pr = hr + d2 * HC + h * C;
  const float* pa = att + h * C;
  float acc = 0.f;
  for (int c = 0; c < C; ++c) {
    float v = pl[c] + pr[c];
    v = (v >= 0.f) ? v : 0.2f * v;
    acc = fmaf(v, pa[c], acc);
  }
  if (valid) {
    ebuf[t] = acc;
    atomicMax(&emax[(d2 << hshift) + h], enc_f(acc));
  } else {
    ebuf[t] = -__builtin_inff();
  }
}

// w = exp(e - emax[dst]); accumulate denominator. Overwrites ebuf with w.
__global__ void edge_w_kernel(const int* __restrict__ dst_a, int E, int total, int hshift,
                              float* __restrict__ ebuf, const unsigned* __restrict__ emax,
                              float* __restrict__ den) {
  int t = blockIdx.x * blockDim.x + threadIdx.x;
  if (t >= total) return;
  int e = t >> hshift, h = t & ((1 << hshift) - 1);
  int d2 = (e < E) ? dst_a[e] : (e - E);
  unsigned enc = emax[(d2 << hshift) + h];
  float m = (enc == 0u) ? 0.f : dec_f(enc);     // enc==0: empty segment, ref uses 0
  float w = expf(ebuf[t] - m);                  // -inf -> 0
  ebuf[t] = w;
  if (w != 0.f) atomicAdd(&den[(d2 << hshift) + h], w);
}

// out[dst] += (w/denom) * hl[src]
__global__ void edge_scatter_kernel(const int* __restrict__ src_a, const int* __restrict__ dst_a,
                                    int E, int total, int hshift, int C,
                                    const float* __restrict__ ebuf, const float* __restrict__ den,
                                    const float* __restrict__ hl, float* __restrict__ out) {
  int t = blockIdx.x * blockDim.x + threadIdx.x;
  if (t >= total) return;
  int e = t >> hshift, h = t & ((1 << hshift) - 1);
  int s, d2;
  if (e < E) { s = src_a[e]; d2 = dst_a[e]; } else { s = d2 = e - E; }
  float w = ebuf[t];
  if (w == 0.f) return;
  float alpha = w / (den[(d2 << hshift) + h] + 1e-16f);
  int HC = C << hshift;
  const float* pl = hl + s * HC + h * C;
  float* po = out + d2 * HC + h * C;
  for (int c = 0; c < C; ++c) atomicAdd(&po[c], alpha * pl[c]);
}

// x = elu(x + b1 [+ b2]) in place, rows of 64
__global__ void elu_bias_kernel(float* __restrict__ x, const float* __restrict__ b1,
                                const float* __restrict__ b2, int n) {
  int t = blockIdx.x * blockDim.x + threadIdx.x;
  if (t >= n * 64) return;
  int col = t & 63;
  float v = x[t] + b1[col] + (b2 ? b2[col] : 0.f);
  x[t] = (v > 0.f) ? v : expm1f(v);
}

// LayerNorm over rows of 64 (one wave per row), input = acc + b1 [+ b2]
__global__ void ln_kernel(const float* __restrict__ acc, const float* __restrict__ b1,
                          const float* __restrict__ b2,
                          const float* __restrict__ lw, const float* __restrict__ lb,
                          float* __restrict__ out, int n) {
  int lane = threadIdx.x & 63;
  int row = blockIdx.x * (blockDim.x >> 6) + (threadIdx.x >> 6);
  if (row >= n) return;
  float v = acc[row * 64 + lane] + b1[lane] + (b2 ? b2[lane] : 0.f);
  float s = v;
  #pragma unroll
  for (int off = 32; off > 0; off >>= 1) s += __shfl_xor(s, off, 64);
  float mu = s * (1.f / 64.f);
  float dv = v - mu;
  float q = dv * dv;
  #pragma unroll
  for (int off = 32; off > 0; off >>= 1) q += __shfl_xor(q, off, 64);
  float var = q * (1.f / 64.f);
  out[row * 64 + lane] = dv * rsqrtf(var + 1e-5f) * lw[lane] + lb[lane];
}

extern "C" void kernel_launch(void* const* d_in, const int* in_sizes, int n_in,
                              void* d_out, int out_size, void* d_ws, size_t ws_size,
                              hipStream_t stream) {
  const float* x_veh = (const float*)d_in[0];
  const float* x_rsu = (const float*)d_in[1];
  const int* ei_v2v = (const int*)d_in[2];
  const int* ei_v2i = (const int*)d_in[3];
  const int* ei_i2v = (const int*)d_in[4];
  const float* P[36];
  for (int i = 0; i < 36; ++i) P[i] = (const float*)d_in[5 + i];
  // blocks of 6: p1v P[0..5], p1i P[6..11], p1r P[12..17], p2v P[18..23], p2i P[24..29], p2r P[30..35]
  // within block: Wl, bl, Wr, br, att, b
  const float* lnv_w = (const float*)d_in[41];
  const float* lnv_b = (const float*)d_in[42];
  const float* lnr_w = (const float*)d_in[43];
  const float* lnr_b = (const float*)d_in[44];

  float* ws = (float*)d_ws;
  float* P0    = ws;                  // 3.2M floats
  float* P1    = P0 + 3200000;        // 3.2M
  float* ACCV  = P1 + 3200000;        // 3.2M (layer1 veh acc -> h_veh)
  float* ACC2V = ACCV + 3200000;      // 3.2M (layer2 veh acc)
  float* S0    = ACC2V + 3200000;     // 32k
  float* S1    = S0 + 32000;          // 32k
  float* ACCR  = S1 + 32000;          // 32k (layer1 rsu acc -> h_rsu)
  float* ACC2R = ACCR + 32000;        // 32k
  float* EBUF  = ACC2R + 32000;       // 900k (per-edge scores/weights)
  unsigned* EMAX = (unsigned*)(EBUF + 900000); // 100k
  float* DEN   = (float*)(EMAX + 100000);      // 100k
  // total ~56.1 MB of d_ws

  auto gsz = [](int n) { return (n + 255) / 256; };

  auto proj = [&](const float* x, const float* W, const float* b, float* out, int n, int d) {
    proj_kernel<<<gsz(n * 64), 256, 0, stream>>>(x, W, b, out, n, d);
  };

  auto conv = [&](const int* src, const int* dst, int E, int nloop, int selfmask,
                  int n_dst, int hshift, const float* hl, const float* hr,
                  const float* att, float* acc) {
    int H = 1 << hshift;
    int C = 64 >> hshift;
    int total = (E + nloop) * H;
    hipMemsetAsync(EMAX, 0, (size_t)n_dst * H * 4, stream);
    hipMemsetAsync(DEN, 0, (size_t)n_dst * H * 4, stream);
    edge_score_kernel<<<gsz(total), 256, 0, stream>>>(src, dst, E, total, selfmask, hshift, C,
                                                      hl, hr, att, EBUF, EMAX);
    edge_w_kernel<<<gsz(total), 256, 0, stream>>>(dst, E, total, hshift, EBUF, EMAX, DEN);
    edge_scatter_kernel<<<gsz(total), 256, 0, stream>>>(src, dst, E, total, hshift, C,
                                                        EBUF, DEN, hl, acc);
  };

  // ================= layer 1 (heads=2, C=32) =================
  // v2v conv (self-loops, masks existing)
  proj(x_veh, P[0], P[1], P0, NV, 6);    // p1v_Wl
  proj(x_veh, P[2], P[3], P1, NV, 6);    // p1v_Wr
  hipMemsetAsync(ACCV, 0, (size_t)NV * 64 * 4, stream);
  conv(ei_v2v, ei_v2v + EVV, EVV, NV, 1, NV, 1, P0, P1, P[4], ACCV);
  // i2v conv (no self-loops), accumulate into same veh acc
  proj(x_rsu, P[12], P[13], S0, NR, 1);  // p1r_Wl
  proj(x_veh, P[14], P[15], P0, NV, 6);  // p1r_Wr
  conv(ei_i2v, ei_i2v + EIV, EIV, 0, 0, NV, 1, S0, P0, P[16], ACCV);
  // h_veh = elu(acc + p1v_b + p1r_b) in place
  elu_bias_kernel<<<gsz(NV * 64), 256, 0, stream>>>(ACCV, P[5], P[17], NV);
  // v2i conv (no self-loops)
  proj(x_veh, P[6], P[7], P0, NV, 6);    // p1i_Wl
  proj(x_rsu, P[8], P[9], S1, NR, 1);    // p1i_Wr
  hipMemsetAsync(ACCR, 0, (size_t)NR * 64 * 4, stream);
  conv(ei_v2i, ei_v2i + EVI, EVI, 0, 0, NR, 1, P0, S1, P[10], ACCR);
  elu_bias_kernel<<<gsz(NR * 64), 256, 0, stream>>>(ACCR, P[11], nullptr, NR);

  // ================= layer 2 (heads=1, C=64) =================
  // v2v conv into ACC2V
  proj(ACCV, P[18], P[19], P0, NV, 64);  // p2v_Wl
  proj(ACCV, P[20], P[21], P1, NV, 64);  // p2v_Wr
  hipMemsetAsync(ACC2V, 0, (size_t)NV * 64 * 4, stream);
  conv(ei_v2v, ei_v2v + EVV, EVV, NV, 1, NV, 0, P0, P1, P[22], ACC2V);
  // i2v conv (self-loops: 500) accumulate into ACC2V
  proj(ACCR, P[30], P[31], S0, NR, 64);  // p2r_Wl
  proj(ACCV, P[32], P[33], P0, NV, 64);  // p2r_Wr
  conv(ei_i2v, ei_i2v + EIV, EIV, NR, 1, NV, 0, S0, P0, P[34], ACC2V);
  // LN veh -> out[0 : 3.2M]
  ln_kernel<<<gsz(NV * 64) , 256, 0, stream>>>(ACC2V, P[23], P[35], lnv_w, lnv_b,
                                               (float*)d_out, NV);
  // v2i conv (self-loops: 500) into ACC2R
  proj(ACCV, P[24], P[25], P0, NV, 64);  // p2i_Wl
  proj(ACCR, P[26], P[27], S1, NR, 64);  // p2i_Wr
  hipMemsetAsync(ACC2R, 0, (size_t)NR * 64 * 4, stream);
  conv(ei_v2i, ei_v2i + EVI, EVI, NR, 1, NR, 0, P0, S1, P[28], ACC2R);
  // LN rsu -> out[3.2M : ]
  ln_kernel<<<gsz(NR * 64), 256, 0, stream>>>(ACC2R, P[29], nullptr, lnr_w, lnr_b,
                                              (float*)d_out + (size_t)NV * 64, NR);
}

// Round 2
// 951.487 us; speedup vs baseline: 6.5687x; 6.5687x over previous
//
#include <hip/hip_runtime.h>
#include <math.h>

#define NV 50000
#define NR 500
#define EVV 400000
#define EVI 100000
#define EIV 100000

// ---------------- dense projection: out[n,64] = x[n,d] @ W[d,64] + b ----------------
__global__ void proj_kernel(const float* __restrict__ x, const float* __restrict__ W,
                            const float* __restrict__ b, float* __restrict__ out,
                            int n, int d) {
  int t = blockIdx.x * blockDim.x + threadIdx.x;
  if (t >= n * 64) return;
  int row = t >> 6, col = t & 63;
  const float* xr = x + (size_t)row * d;
  float acc = b[col];
  for (int k = 0; k < d; ++k) acc = fmaf(xr[k], W[k * 64 + col], acc);
  out[t] = acc;
}

// ---------------- CSR build ----------------
__global__ void hist_kernel(const int* __restrict__ src, const int* __restrict__ dst,
                            int E, unsigned* __restrict__ cnt, int drop_self) {
  int e = blockIdx.x * blockDim.x + threadIdx.x;
  if (e >= E) return;
  if (drop_self && src[e] == dst[e]) return;
  atomicAdd(&cnt[dst[e]], 1u);
}

// single-block (1024 threads) exclusive scan of cnt[0..n) -> rp[0..n]
__global__ void scan_kernel(const unsigned* __restrict__ cnt, unsigned* __restrict__ rp, int n) {
  __shared__ unsigned ssum[1024];
  int t = threadIdx.x;
  int chunk = (n + 1023) / 1024;
  int beg = t * chunk, end = min(beg + chunk, n);
  unsigned s = 0;
  for (int i = beg; i < end; ++i) s += cnt[i];
  ssum[t] = s;
  __syncthreads();
  for (int off = 1; off < 1024; off <<= 1) {
    unsigned v = (t >= off) ? ssum[t - off] : 0u;
    __syncthreads();
    ssum[t] += v;
    __syncthreads();
  }
  unsigned base = (t == 0) ? 0u : ssum[t - 1];
  for (int i = beg; i < end; ++i) { unsigned c = cnt[i]; rp[i] = base; base += c; }
  if (t == 0) rp[n] = ssum[1023];
}

__global__ void fill_kernel(const int* __restrict__ src, const int* __restrict__ dst,
                            int E, unsigned* __restrict__ cursor,
                            int* __restrict__ src_sorted, int drop_self) {
  int e = blockIdx.x * blockDim.x + threadIdx.x;
  if (e >= E) return;
  int sv = src[e], dv = dst[e];
  if (drop_self && sv == dv) return;
  unsigned pos = atomicAdd(&cursor[dv], 1u);
  src_sorted[pos] = sv;
}

// ---------------- fused GATv2 gather (online softmax) ----------------
template <int CC>
__device__ __forceinline__ void online_update(float pl, float hrv, float a,
                                              float& m, float& s, float& acc) {
  float v = pl + hrv;
  v = (v >= 0.f) ? v : 0.2f * v;                 // leaky_relu(0.2)
  float e = v * a;
  #pragma unroll
  for (int off = CC >> 1; off > 0; off >>= 1) e += __shfl_xor(e, off, 64);
  float nm = fmaxf(m, e);
  float f = __expf(m - nm);                      // m=-inf first iter -> 0
  float w = __expf(e - nm);
  s = s * f + w;
  acc = acc * f + w * pl;
  m = nm;
}

// One dst per wave (WPD=1) or one dst per 4-wave block (WPD=4, for the 500-RSU convs).
// lane = h*C + c. nloop: dst<nloop gets a self-loop edge (src=dst index, hl table).
// selfmask: skip stored edges whose raw src index == raw dst index.
template <int WPD, int CC>
__global__ void gat_gather_kernel(const unsigned* __restrict__ rp,
                                  const int* __restrict__ src_sorted,
                                  const float* __restrict__ hl,
                                  const float* __restrict__ hr,
                                  const float* __restrict__ att,
                                  float* __restrict__ out,
                                  int n_dst, int nloop, int selfmask) {
  int lane = threadIdx.x & 63;
  int wid = threadIdx.x >> 6;
  int d = (WPD == 1) ? (blockIdx.x * 4 + wid) : blockIdx.x;
  if (d >= n_dst) return;
  float a = att[lane];
  float hrv = hr[(size_t)d * 64 + lane];
  float m = -INFINITY, s = 0.f, acc = 0.f;
  unsigned beg = rp[d], end = rp[d + 1];
  for (unsigned i = beg + (WPD == 1 ? 0u : (unsigned)wid); i < end; i += WPD) {
    int sv = src_sorted[i];
    if (selfmask && sv == d) continue;           // wave-uniform branch
    float pl = hl[(size_t)sv * 64 + lane];
    online_update<CC>(pl, hrv, a, m, s, acc);
  }
  // self loop handled by wave 0's partial
  if ((WPD == 1 || wid == 0) && d < nloop) {
    float pl = hl[(size_t)d * 64 + lane];
    online_update<CC>(pl, hrv, a, m, s, acc);
  }
  if (WPD == 1) {
    out[(size_t)d * 64 + lane] += acc / (s + 1e-16f);
  } else {
    __shared__ float sm[WPD][64], ss[WPD][64], sacc[WPD][64];
    sm[wid][lane] = m; ss[wid][lane] = s; sacc[wid][lane] = acc;
    __syncthreads();
    if (wid == 0) {
      float M = -INFINITY;
      #pragma unroll
      for (int w2 = 0; w2 < WPD; ++w2) M = fmaxf(M, sm[w2][lane]);
      float S = 0.f, A = 0.f;
      #pragma unroll
      for (int w2 = 0; w2 < WPD; ++w2) {
        float mw = sm[w2][lane];
        float f = (mw == -INFINITY) ? 0.f : __expf(mw - M);
        S += ss[w2][lane] * f;
        A += sacc[w2][lane] * f;
      }
      out[(size_t)d * 64 + lane] += A / (S + 1e-16f);
    }
  }
}

// ---------------- epilogues ----------------
__global__ void elu_bias_kernel(float* __restrict__ x, const float* __restrict__ b1,
                                const float* __restrict__ b2, int n) {
  int t = blockIdx.x * blockDim.x + threadIdx.x;
  if (t >= n * 64) return;
  int col = t & 63;
  float v = x[t] + b1[col] + (b2 ? b2[col] : 0.f);
  x[t] = (v > 0.f) ? v : expm1f(v);
}

__global__ void ln_kernel(const float* __restrict__ acc, const float* __restrict__ b1,
                          const float* __restrict__ b2,
                          const float* __restrict__ lw, const float* __restrict__ lb,
                          float* __restrict__ out, int n) {
  int lane = threadIdx.x & 63;
  int row = blockIdx.x * (blockDim.x >> 6) + (threadIdx.x >> 6);
  if (row >= n) return;
  float v = acc[row * 64 + lane] + b1[lane] + (b2 ? b2[lane] : 0.f);
  float s = v;
  #pragma unroll
  for (int off = 32; off > 0; off >>= 1) s += __shfl_xor(s, off, 64);
  float mu = s * (1.f / 64.f);
  float dv = v - mu;
  float q = dv * dv;
  #pragma unroll
  for (int off = 32; off > 0; off >>= 1) q += __shfl_xor(q, off, 64);
  float var = q * (1.f / 64.f);
  out[row * 64 + lane] = dv * rsqrtf(var + 1e-5f) * lw[lane] + lb[lane];
}

extern "C" void kernel_launch(void* const* d_in, const int* in_sizes, int n_in,
                              void* d_out, int out_size, void* d_ws, size_t ws_size,
                              hipStream_t stream) {
  const float* x_veh = (const float*)d_in[0];
  const float* x_rsu = (const float*)d_in[1];
  const int* ei_v2v = (const int*)d_in[2];
  const int* ei_v2i = (const int*)d_in[3];
  const int* ei_i2v = (const int*)d_in[4];
  const float* P[36];
  for (int i = 0; i < 36; ++i) P[i] = (const float*)d_in[5 + i];
  // blocks of 6: p1v P[0..5], p1i P[6..11], p1r P[12..17], p2v P[18..23], p2i P[24..29], p2r P[30..35]
  const float* lnv_w = (const float*)d_in[41];
  const float* lnv_b = (const float*)d_in[42];
  const float* lnr_w = (const float*)d_in[43];
  const float* lnr_b = (const float*)d_in[44];

  float* ws = (float*)d_ws;
  float* P0    = ws;                  // 3.2M floats
  float* P1    = P0 + 3200000;
  float* ACCV  = P1 + 3200000;        // h_veh
  float* ACC2V = ACCV + 3200000;
  float* S0    = ACC2V + 3200000;     // 32k
  float* S1    = S0 + 32000;
  float* ACCR  = S1 + 32000;          // h_rsu
  float* ACC2R = ACCR + 32000;
  unsigned* rp_vv  = (unsigned*)(ACC2R + 32000);   // 50001
  unsigned* rp_iv  = rp_vv + (NV + 1);             // 50001
  unsigned* rp_vi  = rp_iv + (NV + 1);             // 501
  int* src_vv = (int*)(rp_vi + (NR + 1));          // 400000
  int* src_iv = src_vv + EVV;                      // 100000
  int* src_vi = src_iv + EIV;                      // 100000
  unsigned* cnt    = (unsigned*)(src_vi + EVI);    // 50001
  unsigned* cursor = cnt + (NV + 1);               // 50001

  auto gsz = [](int n) { return (n + 255) / 256; };

  auto proj = [&](const float* x, const float* W, const float* b, float* out, int n, int d) {
    proj_kernel<<<gsz(n * 64), 256, 0, stream>>>(x, W, b, out, n, d);
  };

  auto build = [&](const int* src, const int* dst, int E, int n_dst,
                   unsigned* rp, int* ssorted, int drop) {
    hipMemsetAsync(cnt, 0, (size_t)n_dst * 4, stream);
    hist_kernel<<<gsz(E), 256, 0, stream>>>(src, dst, E, cnt, drop);
    scan_kernel<<<1, 1024, 0, stream>>>(cnt, rp, n_dst);
    hipMemcpyAsync(cursor, rp, (size_t)n_dst * 4, hipMemcpyDeviceToDevice, stream);
    fill_kernel<<<gsz(E), 256, 0, stream>>>(src, dst, E, cursor, ssorted, drop);
  };

  // CSRs (v2v drops raw self-edges at build: both v2v convs mask them)
  build(ei_v2v, ei_v2v + EVV, EVV, NV, rp_vv, src_vv, 1);
  build(ei_v2i, ei_v2i + EVI, EVI, NR, rp_vi, src_vi, 0);
  build(ei_i2v, ei_i2v + EIV, EIV, NV, rp_iv, src_iv, 0);

  // ================= layer 1 (heads=2, C=32) =================
  proj(x_veh, P[0], P[1], P0, NV, 6);    // p1v_Wl
  proj(x_veh, P[2], P[3], P1, NV, 6);    // p1v_Wr
  hipMemsetAsync(ACCV, 0, (size_t)NV * 64 * 4, stream);
  gat_gather_kernel<1, 32><<<gsz(NV * 64), 256, 0, stream>>>(rp_vv, src_vv, P0, P1, P[4],
                                                             ACCV, NV, NV, 0);
  proj(x_rsu, P[12], P[13], S0, NR, 1);  // p1r_Wl
  proj(x_veh, P[14], P[15], P0, NV, 6);  // p1r_Wr
  gat_gather_kernel<1, 32><<<gsz(NV * 64), 256, 0, stream>>>(rp_iv, src_iv, S0, P0, P[16],
                                                             ACCV, NV, 0, 0);
  elu_bias_kernel<<<gsz(NV * 64), 256, 0, stream>>>(ACCV, P[5], P[17], NV);

  proj(x_veh, P[6], P[7], P0, NV, 6);    // p1i_Wl
  proj(x_rsu, P[8], P[9], S1, NR, 1);    // p1i_Wr
  hipMemsetAsync(ACCR, 0, (size_t)NR * 64 * 4, stream);
  gat_gather_kernel<4, 32><<<NR, 256, 0, stream>>>(rp_vi, src_vi, P0, S1, P[10],
                                                   ACCR, NR, 0, 0);
  elu_bias_kernel<<<gsz(NR * 64), 256, 0, stream>>>(ACCR, P[11], nullptr, NR);

  // ================= layer 2 (heads=1, C=64) =================
  proj(ACCV, P[18], P[19], P0, NV, 64);  // p2v_Wl
  proj(ACCV, P[20], P[21], P1, NV, 64);  // p2v_Wr
  hipMemsetAsync(ACC2V, 0, (size_t)NV * 64 * 4, stream);
  gat_gather_kernel<1, 64><<<gsz(NV * 64), 256, 0, stream>>>(rp_vv, src_vv, P0, P1, P[22],
                                                             ACC2V, NV, NV, 0);
  proj(ACCR, P[30], P[31], S0, NR, 64);  // p2r_Wl
  proj(ACCV, P[32], P[33], P0, NV, 64);  // p2r_Wr
  gat_gather_kernel<1, 64><<<gsz(NV * 64), 256, 0, stream>>>(rp_iv, src_iv, S0, P0, P[34],
                                                             ACC2V, NV, NR, 1);
  ln_kernel<<<gsz(NV * 64), 256, 0, stream>>>(ACC2V, P[23], P[35], lnv_w, lnv_b,
                                              (float*)d_out, NV);

  proj(ACCV, P[24], P[25], P0, NV, 64);  // p2i_Wl
  proj(ACCR, P[26], P[27], S1, NR, 64);  // p2i_Wr
  hipMemsetAsync(ACC2R, 0, (size_t)NR * 64 * 4, stream);
  gat_gather_kernel<4, 64><<<NR, 256, 0, stream>>>(rp_vi, src_vi, P0, S1, P[28],
                                                   ACC2R, NR, NR, 1);
  ln_kernel<<<gsz(NR * 64), 256, 0, stream>>>(ACC2R, P[29], nullptr, lnr_w, lnr_b,
                                              (float*)d_out + (size_t)NV * 64, NR);
}